// Round 5
// baseline (200.160 us; speedup 1.0000x reference)
//
#include <hip/hip_runtime.h>

#define N_BCH 64
#define N_DIM 64
#define N_COL 32

typedef float f32x4 __attribute__((ext_vector_type(4)));

// ---------------------------------------------------------------------------
// Fused kernel. Hot loop is byte-identical to round-4's known-good wtmd_main
// (~6.2 TB/s). Epilogue fused via last-block-done: per-block partials ->
// d_ws, device-scope release (one __threadfence per block, after
// __syncthreads drains all waves' stores to L2), atomic counter, last block
// acquires and reduces. Block 0 writes the trivial col/prc_new outputs up
// front (overlapped with the hill loop).
// d_ws layout: partial[64][gridDim.x] f32, then one u32 counter (memset to 0
// on the stream each call).
// ---------------------------------------------------------------------------
__global__ __launch_bounds__(512, 8) void wtmd_fused(
    const float* __restrict__ col_var,
    const float* __restrict__ mtd_cen,
    const float* __restrict__ mtd_prc,
    const float* __restrict__ mtd_hgt,
    const float* __restrict__ kbt,
    const float* __restrict__ prc,
    const float* __restrict__ hgt,   // scalar
    const float* __restrict__ gam,   // scalar
    const float* __restrict__ pbc,
    const int*   __restrict__ msk,
    float*       __restrict__ partial,   // [64][gridDim.x]
    unsigned*    __restrict__ counter,   // pre-zeroed each call
    int n_hil,
    float*       __restrict__ out)
{
    const int t  = threadIdx.x;     // 0..511
    const int b  = t >> 3;          // 0..63
    const int c0 = (4 * t) & 31;    // column base
    const int stride = gridDim.x;

    // Trivial outputs, overlapped with everyone else's hill loop.
    if (blockIdx.x == 0) {
        for (int i = t; i < N_BCH * N_COL; i += 512) {
            const int bb = i >> 5;
            const int c  = i & 31;
            out[i]        = col_var[bb * N_DIM + msk[c]];
            out[2048 + i] = prc[c];
        }
    }

    float col[4], pb[4], ipb[4];
#pragma unroll
    for (int j = 0; j < 4; ++j) {
        const int c = c0 + j;
        col[j] = col_var[b * N_DIM + msk[c]];
        const float p = pbc[c];
        pb[j]  = p;
        // when p<=0: ipb=0 -> rintf(0)=0 -> no wrap applied (matches reference)
        ipb[j] = (p > 0.f) ? (1.0f / p) : 0.f;
    }

    float acc = 0.f;

    for (int h = blockIdx.x; h < n_hil; h += stride) {
        const size_t base = (size_t)h * (N_BCH * N_COL) + 4 * (size_t)t;
        const f32x4 cen = __builtin_nontemporal_load((const f32x4*)(mtd_cen + base));
        const f32x4 pr  = __builtin_nontemporal_load((const f32x4*)(mtd_prc + base));
        const float hg  = __builtin_nontemporal_load(mtd_hgt + (size_t)h * N_BCH + b);

        float s = 0.f;
#pragma unroll
        for (int j = 0; j < 4; ++j) {
            float d = col[j] - cen[j];
            d -= pb[j] * rintf(d * ipb[j]);
            s = fmaf(pr[j] * d, d, s);
        }

        // reduce across the 8 lanes sharing this batch
#pragma unroll
        for (int m = 1; m < 8; m <<= 1)
            s += __shfl_xor(s, m);

        acc += hg * __expf(-0.5f * s);
    }

    if ((t & 7) == 0)
        partial[(size_t)b * stride + blockIdx.x] = acc;

    // ---- last-block-done tail ----
    __shared__ unsigned is_last;
    __syncthreads();   // each wave drains vmcnt before barrier -> stores in L2
    if (t == 0) {
        __threadfence();   // release: write back this XCD's L2 (one per block)
        is_last = (atomicAdd(counter, 1u) == (unsigned)(gridDim.x - 1));
    }
    __syncthreads();
    if (!is_last) return;
    if (t == 0) __threadfence();   // acquire: invalidate L1/L2 before reading
    __syncthreads();

    __shared__ float red[512];
    const int bb = t & 63;
    const int s8 = t >> 6;                 // 0..7 stripes
    const float* row = partial + (size_t)bb * stride;
    float a = 0.f;
    for (int g = 4 * s8; g < stride; g += 32) {
        const f32x4 v = *(const f32x4*)(row + g);
        a += (v[0] + v[1]) + (v[2] + v[3]);
    }
    red[t] = a;
    __syncthreads();
    if (t < 64) {
        float eng = 0.f;
#pragma unroll
        for (int q = 0; q < 8; ++q) eng += red[t + 64 * q];
        const float k   = kbt[t];
        const float det = gam[0] * k - k;
        out[4096 + t] = hgt[0] * __expf(-eng / det);
    }
}

extern "C" void kernel_launch(void* const* d_in, const int* in_sizes, int n_in,
                              void* d_out, int out_size, void* d_ws, size_t ws_size,
                              hipStream_t stream) {
    const float* col_var = (const float*)d_in[0];
    const float* mtd_cen = (const float*)d_in[1];
    const float* mtd_prc = (const float*)d_in[2];
    const float* mtd_hgt = (const float*)d_in[3];
    const float* kbt     = (const float*)d_in[4];
    const float* prc     = (const float*)d_in[5];
    const float* hgt     = (const float*)d_in[6];
    const float* gam     = (const float*)d_in[7];
    const float* pbc     = (const float*)d_in[8];
    const int*   msk     = (const int*)d_in[9];
    float* out     = (float*)d_out;
    float* partial = (float*)d_ws;

    const int n_hil = in_sizes[3] / N_BCH;   // mtd_hgt is (n_hil, 64)

    // 1024 blocks x 8 waves = 32 waves/CU on 256 CUs.
    int nblocks = 1024;
    const size_t per_block = (size_t)N_BCH * sizeof(float);
    if (ws_size < (size_t)nblocks * per_block + sizeof(unsigned))
        nblocks = (int)((ws_size - sizeof(unsigned)) / per_block);
    nblocks &= ~3;                // multiple of 4 for float4 reduce
    if (nblocks < 4) nblocks = 4;

    unsigned* counter = (unsigned*)((char*)d_ws + (size_t)nblocks * per_block);
    hipMemsetAsync(counter, 0, sizeof(unsigned), stream);

    wtmd_fused<<<nblocks, 512, 0, stream>>>(col_var, mtd_cen, mtd_prc, mtd_hgt,
                                            kbt, prc, hgt, gam, pbc, msk,
                                            partial, counter, n_hil, out);
}

// Round 6
// 134.931 us; speedup vs baseline: 1.4834x; 1.4834x over previous
//
#include <hip/hip_runtime.h>

#define N_BCH 64
#define N_DIM 64
#define N_COL 32

typedef float f32x4 __attribute__((ext_vector_type(4)));

// ---------------------------------------------------------------------------
// Main kernel (round-4 known-good: ~6.2-6.3 TB/s, HBM-roofline).
// eng[b] = sum_h mtd_hgt[h,b] * exp(-0.5 * sum_c prc*wrap(diff)^2)
// Block = 512 threads (8 waves). Thread t owns 4 columns ((4t)&31) of batch
// t>>3 — one float4 per array per hill, fully coalesced. Grid-stride over
// hills; per-block partials written transposed to d_ws ([64][nblocks]).
// NOTE (measured, rounds 3/5): do NOT manually stride-unroll this loop
// (breaks compiler pipelining, 4.4x/hill cost) and do NOT fuse the reduce
// via last-block-done (__threadfence = per-block L2 writeback/invalidate
// mid-stream, +60 us).
// ---------------------------------------------------------------------------
__global__ __launch_bounds__(512, 8) void wtmd_main(
    const float* __restrict__ col_var,
    const float* __restrict__ mtd_cen,
    const float* __restrict__ mtd_prc,
    const float* __restrict__ mtd_hgt,
    const float* __restrict__ pbc,
    const int*   __restrict__ msk,
    float*       __restrict__ partial,   // [64][gridDim.x]  (transposed)
    int n_hil)
{
    const int t  = threadIdx.x;     // 0..511
    const int b  = t >> 3;          // 0..63
    const int c0 = (4 * t) & 31;    // column base

    float col[4], pb[4], ipb[4];
#pragma unroll
    for (int j = 0; j < 4; ++j) {
        const int c = c0 + j;
        col[j] = col_var[b * N_DIM + msk[c]];
        const float p = pbc[c];
        pb[j]  = p;
        // when p<=0: ipb=0 -> rintf(0)=0 -> no wrap applied (matches reference)
        ipb[j] = (p > 0.f) ? (1.0f / p) : 0.f;
    }

    float acc = 0.f;
    const int stride = gridDim.x;

    for (int h = blockIdx.x; h < n_hil; h += stride) {
        const size_t base = (size_t)h * (N_BCH * N_COL) + 4 * (size_t)t;
        const f32x4 cen = __builtin_nontemporal_load((const f32x4*)(mtd_cen + base));
        const f32x4 pr  = __builtin_nontemporal_load((const f32x4*)(mtd_prc + base));
        const float hg  = __builtin_nontemporal_load(mtd_hgt + (size_t)h * N_BCH + b);

        float s = 0.f;
#pragma unroll
        for (int j = 0; j < 4; ++j) {
            float d = col[j] - cen[j];
            d -= pb[j] * rintf(d * ipb[j]);
            s = fmaf(pr[j] * d, d, s);
        }

        // reduce across the 8 lanes sharing this batch
#pragma unroll
        for (int m = 1; m < 8; m <<= 1)
            s += __shfl_xor(s, m);

        acc += hg * __expf(-0.5f * s);
    }

    if ((t & 7) == 0)
        partial[(size_t)b * stride + blockIdx.x] = acc;
}

// ---------------------------------------------------------------------------
// Epilogue: 65 blocks. Blocks 0..63 each reduce one batch row of partial
// (contiguous float4 loads) and write hgt_wt[b]. Block 64 writes col/prc_new.
// out[0..2047] = col, out[2048..4095] = prc_new, out[4096..4159] = hgt_wt.
// ---------------------------------------------------------------------------
__global__ __launch_bounds__(256) void wtmd_epi(
    const float* __restrict__ col_var,
    const float* __restrict__ kbt,
    const float* __restrict__ prc,
    const float* __restrict__ hgt,   // scalar
    const float* __restrict__ gam,   // scalar
    const int*   __restrict__ msk,
    const float* __restrict__ partial,
    int nblocks,                      // multiple of 4
    float*       __restrict__ out)
{
    const int t   = threadIdx.x;
    const int blk = blockIdx.x;

    if (blk == 64) {
        for (int i = t; i < N_BCH * N_COL; i += 256) {
            const int bb = i >> 5;
            const int c  = i & 31;
            out[i]        = col_var[bb * N_DIM + msk[c]];
            out[2048 + i] = prc[c];
        }
        return;
    }

    // Reduce batch row `blk` of partial[64][nblocks].
    const float* row = partial + (size_t)blk * nblocks;
    float acc = 0.f;
    for (int g = 4 * t; g < nblocks; g += 1024) {
        const f32x4 v = *(const f32x4*)(row + g);
        acc += (v[0] + v[1]) + (v[2] + v[3]);
    }

    __shared__ float red[256];
    red[t] = acc;
    __syncthreads();

    if (t < 64) {
        float a = (red[t] + red[t + 64]) + (red[t + 128] + red[t + 192]);
#pragma unroll
        for (int m = 32; m >= 1; m >>= 1)
            a += __shfl_xor(a, m);
        if (t == 0) {
            const float k   = kbt[blk];
            const float det = gam[0] * k - k;
            out[4096 + blk] = hgt[0] * __expf(-a / det);
        }
    }
}

extern "C" void kernel_launch(void* const* d_in, const int* in_sizes, int n_in,
                              void* d_out, int out_size, void* d_ws, size_t ws_size,
                              hipStream_t stream) {
    const float* col_var = (const float*)d_in[0];
    const float* mtd_cen = (const float*)d_in[1];
    const float* mtd_prc = (const float*)d_in[2];
    const float* mtd_hgt = (const float*)d_in[3];
    const float* kbt     = (const float*)d_in[4];
    const float* prc     = (const float*)d_in[5];
    const float* hgt     = (const float*)d_in[6];
    const float* gam     = (const float*)d_in[7];
    const float* pbc     = (const float*)d_in[8];
    const int*   msk     = (const int*)d_in[9];
    float* out     = (float*)d_out;
    float* partial = (float*)d_ws;

    const int n_hil = in_sizes[3] / N_BCH;   // mtd_hgt is (n_hil, 64)

    // 1024 blocks x 8 waves = 32 waves/CU on 256 CUs.
    int nblocks = 1024;
    const size_t per_block = (size_t)N_BCH * sizeof(float);
    if (ws_size < (size_t)nblocks * per_block)
        nblocks = (int)(ws_size / per_block);
    nblocks &= ~3;                // multiple of 4 for float4 reduce
    if (nblocks < 4) nblocks = 4;

    wtmd_main<<<nblocks, 512, 0, stream>>>(col_var, mtd_cen, mtd_prc, mtd_hgt,
                                           pbc, msk, partial, n_hil);
    wtmd_epi<<<65, 256, 0, stream>>>(col_var, kbt, prc, hgt, gam, msk,
                                     partial, nblocks, out);
}